// Round 1
// baseline (130.672 us; speedup 1.0000x reference)
//
#include <hip/hip_runtime.h>
#include <hip/hip_bf16.h>

typedef float f32x4 __attribute__((ext_vector_type(4)));
typedef __bf16 bf16x8 __attribute__((ext_vector_type(8)));

#define CC   64
#define HID  256
#define NOUT 64
#define HOUT 384

// ---- kernel A: G[b][iy][ix][k] = b1[k] + sum_c res[b][c][iy][ix] * w1[c][k]
__global__ __launch_bounds__(256) void k_gfeat(const float* __restrict__ res,
                                               const float* __restrict__ w1,
                                               const float* __restrict__ b1,
                                               float* __restrict__ G) {
    int cell = blockIdx.x;            // b*4096 + iy*64 + ix
    int k = threadIdx.x;              // 0..255
    int b = cell >> 12;
    int iyix = cell & 4095;
    __shared__ float feat[CC];
    if (k < CC) feat[k] = res[((b * CC + k) << 12) + iyix];
    __syncthreads();
    float g = b1[k];
#pragma unroll
    for (int c = 0; c < CC; ++c)
        g = fmaf(feat[c], w1[c * HID + k], g);
    G[((size_t)cell << 8) + k] = g;
}

// ---- kernel B: pre-shuffle w2 into MFMA B-fragment order, bf16
// frag element f = ((kstep*4+ng)*64 + lane)*8 + e  <->  w2[kstep*32 + (lane>>4)*8 + e][ng*16 + (lane&15)]
__global__ __launch_bounds__(256) void k_w2f(const float* __restrict__ w2,
                                             __bf16* __restrict__ W2F) {
    int f = blockIdx.x * 256 + threadIdx.x;   // 0..16383
    int e = f & 7;
    int l = (f >> 3) & 63;
    int grp = f >> 9;                 // kstep*4 + ng
    int kstep = grp >> 2, ng = grp & 3;
    int k = kstep * 32 + ((l >> 4) << 3) + e;
    int n = (ng << 4) + (l & 15);
    W2F[f] = (__bf16)w2[k * NOUT + n];
}

// ---- main kernel: tile = 4 rows x 16 cols of pixels, one batch entry per block.z
// wave w handles pixel row i0+w; A-frag row (l&15) = dj; fused layer1 in f32,
// layer2 = 8 K-steps of mfma_f32_16x16x32_bf16 over N=64 (4 groups).
__global__ __launch_bounds__(256) void k_main(const float* __restrict__ G,
                                              const __bf16* __restrict__ W2F,
                                              const float* __restrict__ w1,
                                              const float* __restrict__ b2,
                                              float* __restrict__ out) {
    const int jt = blockIdx.x;        // 0..23
    const int it = blockIdx.y;        // 0..95
    const int b  = blockIdx.z;        // 0..1
    const int tid = threadIdx.x;
    const int wv  = tid >> 6;         // wave id = di
    const int l   = tid & 63;
    const int lhi = l >> 4;           // k-chunk group
    const int dj  = l & 15;           // pixel col within tile / MFMA col
    const int i0 = it * 4, j0 = jt * 16;
    const int i = i0 + wv;
    const int j = j0 + dj;

    // per-pixel corner parameters (duplicated across the 4 quarter-waves)
    const float cyq = -1.f + (2 * i + 1) / 384.f;
    const float cxq = -1.f + (2 * j + 1) / 384.f;
    float relY[4], relX[4], wgt[4], area[4];
    int gofs[4];
#pragma unroll
    for (int c = 0; c < 4; ++c) {
        float vx = (c & 2) ? 1.f : -1.f;   // perturbs y (ref: outer loop)
        float vy = (c & 1) ? 1.f : -1.f;   // perturbs x
        float cy = cyq + vx * (1.f / 384.f) + 1e-6f;
        float cx = cxq + vy * (1.f / 384.f) + 1e-6f;
        cy = fminf(fmaxf(cy, -1.f + 1e-6f), 1.f - 1e-6f);
        cx = fminf(fmaxf(cx, -1.f + 1e-6f), 1.f - 1e-6f);
        int iy = (int)roundf(((cy + 1.f) * 64.f - 1.f) * 0.5f);
        iy = min(max(iy, 0), 63);
        int ix = (int)roundf(((cx + 1.f) * 64.f - 1.f) * 0.5f);
        ix = min(max(ix, 0), 63);
        float ry = (cyq - (-1.f + (2 * iy + 1) / 64.f)) * 64.f;
        float rx = (cxq - (-1.f + (2 * ix + 1) / 64.f)) * 64.f;
        relY[c] = ry; relX[c] = rx;
        area[c] = fabsf(ry * rx) + 1e-9f;
        gofs[c] = ((b << 12) + (iy << 6) + ix) << 8;
    }
    const float inv = 1.f / (area[0] + area[1] + area[2] + area[3]);
    wgt[0] = area[3] * inv;  // diagonal swap (3,2,1,0)
    wgt[1] = area[2] * inv;
    wgt[2] = area[1] * inv;
    wgt[3] = area[0] * inv;

    const float* up = w1 + CC * HID;        // w1 row 64 (rel_y)
    const float* vp = w1 + (CC + 1) * HID;  // w1 row 65 (rel_x)
    const bf16x8* W2v = (const bf16x8*)W2F;

    f32x4 acc[4];
#pragma unroll
    for (int ng = 0; ng < 4; ++ng) acc[ng] = (f32x4){0.f, 0.f, 0.f, 0.f};

#pragma unroll 2
    for (int ks = 0; ks < 8; ++ks) {
        const int k0 = ks * 32 + (lhi << 3);
        f32x4 ua = *(const f32x4*)(up + k0);
        f32x4 ub = *(const f32x4*)(up + k0 + 4);
        f32x4 va = *(const f32x4*)(vp + k0);
        f32x4 vb = *(const f32x4*)(vp + k0 + 4);
        float h[8];
#pragma unroll
        for (int e = 0; e < 8; ++e) h[e] = 0.f;
#pragma unroll
        for (int c = 0; c < 4; ++c) {
            const float* gp = G + gofs[c] + k0;
            f32x4 ga = *(const f32x4*)gp;
            f32x4 gb = *(const f32x4*)(gp + 4);
            const float ry = relY[c], rx = relX[c], wc = wgt[c];
#pragma unroll
            for (int e = 0; e < 4; ++e) {
                float t = fmaf(ry, ua[e], ga[e]);
                t = fmaf(rx, va[e], t);
                h[e] = fmaf(wc, fmaxf(t, 0.f), h[e]);
                float t2 = fmaf(ry, ub[e], gb[e]);
                t2 = fmaf(rx, vb[e], t2);
                h[e + 4] = fmaf(wc, fmaxf(t2, 0.f), h[e + 4]);
            }
        }
        bf16x8 af;
#pragma unroll
        for (int e = 0; e < 8; ++e) af[e] = (__bf16)h[e];
#pragma unroll
        for (int ng = 0; ng < 4; ++ng) {
            bf16x8 bfr = W2v[(ks * 4 + ng) * 64 + l];
            acc[ng] = __builtin_amdgcn_mfma_f32_16x16x32_bf16(af, bfr, acc[ng], 0, 0, 0);
        }
    }

    // epilogue: transpose through padded LDS, coalesced 64B-line writes
    __shared__ float lds[64 * 67];
#pragma unroll
    for (int ng = 0; ng < 4; ++ng) {
        const int o = (ng << 4) + dj;       // MFMA col = l&15 = output channel in group
        const float bb = b2[o];
#pragma unroll
        for (int r = 0; r < 4; ++r) {
            const int p = (wv << 4) + (lhi << 2) + r;  // D row = pixel dj index
            lds[p * 67 + o] = acc[ng][r] + bb;
        }
    }
    __syncthreads();
    const int dj2 = tid & 15, di2 = (tid >> 4) & 3, ob = tid >> 6;
#pragma unroll
    for (int ii = 0; ii < 16; ++ii) {
        const int o = ob + (ii << 2);
        out[((b * NOUT + o) * HOUT + (i0 + di2)) * HOUT + (j0 + dj2)] =
            lds[(di2 * 16 + dj2) * 67 + o];
    }
}

extern "C" void kernel_launch(void* const* d_in, const int* in_sizes, int n_in,
                              void* d_out, int out_size, void* d_ws, size_t ws_size,
                              hipStream_t stream) {
    const float* res = (const float*)d_in[0];
    const float* w1  = (const float*)d_in[1];
    const float* b1  = (const float*)d_in[2];
    const float* w2  = (const float*)d_in[3];
    const float* b2  = (const float*)d_in[4];
    float* out = (float*)d_out;

    float*  G   = (float*)d_ws;                               // 2*4096*256 f32 = 8 MB
    __bf16* W2F = (__bf16*)((char*)d_ws + (size_t)(8u << 20)); // 32 KB

    k_gfeat<<<2 * 64 * 64, 256, 0, stream>>>(res, w1, b1, G);
    k_w2f<<<64, 256, 0, stream>>>(w2, W2F);
    k_main<<<dim3(24, 96, 2), 256, 0, stream>>>(G, W2F, w1, b2, out);
}

// Round 2
// 105.371 us; speedup vs baseline: 1.2401x; 1.2401x over previous
//
#include <hip/hip_runtime.h>
#include <hip/hip_bf16.h>

typedef float f32x2 __attribute__((ext_vector_type(2)));
typedef float f32x4 __attribute__((ext_vector_type(4)));
typedef __bf16 bf16x8 __attribute__((ext_vector_type(8)));

#define CC   64
#define HID  256
#define NOUT 64
#define HOUT 384

// ---- kernel A: G[cell][k] = b1[k] + sum_c res[b][c][iy][ix] * w1[c][k]
// 8 cells per block to amortize w1 traffic.
__global__ __launch_bounds__(256) void k_gfeat(const float* __restrict__ res,
                                               const float* __restrict__ w1,
                                               const float* __restrict__ b1,
                                               float* __restrict__ G) {
    const int cell0 = blockIdx.x * 8;     // 8 cells: cell = b*4096 + iy*64 + ix
    const int k = threadIdx.x;            // 0..255
    __shared__ float feat[8][CC];
    // load 8*64 = 512 floats with 256 threads
#pragma unroll
    for (int t = 0; t < 2; ++t) {
        int idx = t * 256 + k;            // 0..511
        int cc = idx >> 6, c = idx & 63;
        int cell = cell0 + cc;
        int b = cell >> 12, iyix = cell & 4095;
        feat[cc][c] = res[((b * CC + c) << 12) + iyix];
    }
    __syncthreads();
    float g[8];
    const float bk = b1[k];
#pragma unroll
    for (int cc = 0; cc < 8; ++cc) g[cc] = bk;
#pragma unroll
    for (int c = 0; c < CC; ++c) {
        const float w = w1[c * HID + k];
#pragma unroll
        for (int cc = 0; cc < 8; ++cc) g[cc] = fmaf(feat[cc][c], w, g[cc]);
    }
#pragma unroll
    for (int cc = 0; cc < 8; ++cc)
        G[((size_t)(cell0 + cc) << 8) + k] = g[cc];
}

// ---- kernel B: pre-shuffle w2 into MFMA B-fragment order, bf16
// frag element f = ((kstep*4+ng)*64 + lane)*8 + e  <->  w2[kstep*32 + (lane>>4)*8 + e][ng*16 + (lane&15)]
__global__ __launch_bounds__(256) void k_w2f(const float* __restrict__ w2,
                                             __bf16* __restrict__ W2F) {
    int f = blockIdx.x * 256 + threadIdx.x;   // 0..16383
    int e = f & 7;
    int l = (f >> 3) & 63;
    int grp = f >> 9;                 // kstep*4 + ng
    int kstep = grp >> 2, ng = grp & 3;
    int k = kstep * 32 + ((l >> 4) << 3) + e;
    int n = (ng << 4) + (l & 15);
    W2F[f] = (__bf16)w2[k * NOUT + n];
}

// ---- main kernel: 1 wave per block, 16 pixels (one row-strip) per wave.
// A-frag row (l&15) = pixel col dj; k-chunk = l>>4. Fully unrolled K-loop
// with immediate-offset loads; f32x2 math for v_pk_fma_f32.
__global__ __launch_bounds__(64, 4) void k_main(const float* __restrict__ G,
                                                const __bf16* __restrict__ W2F,
                                                const float* __restrict__ w1,
                                                const float* __restrict__ b2,
                                                float* __restrict__ out) {
    const int jt = blockIdx.x;        // 0..23
    const int i  = blockIdx.y;        // 0..383
    const int b  = blockIdx.z;        // 0..1
    const int l  = threadIdx.x;       // 0..63
    const int dj = l & 15;            // pixel col within strip / MFMA A-row
    const int lhi = l >> 4;           // k-chunk group
    const int j0 = jt * 16;
    const int j = j0 + dj;

    // per-pixel corner parameters
    const float cyq = -1.f + (2 * i + 1) / 384.f;
    const float cxq = -1.f + (2 * j + 1) / 384.f;
    float relY[4], relX[4], wgt[4], area[4];
    int gofs[4];
#pragma unroll
    for (int c = 0; c < 4; ++c) {
        float vx = (c & 2) ? 1.f : -1.f;   // perturbs y (ref outer loop)
        float vy = (c & 1) ? 1.f : -1.f;   // perturbs x
        float cy = cyq + vx * (1.f / 384.f) + 1e-6f;
        float cx = cxq + vy * (1.f / 384.f) + 1e-6f;
        cy = fminf(fmaxf(cy, -1.f + 1e-6f), 1.f - 1e-6f);
        cx = fminf(fmaxf(cx, -1.f + 1e-6f), 1.f - 1e-6f);
        int iy = (int)roundf(((cy + 1.f) * 64.f - 1.f) * 0.5f);
        iy = min(max(iy, 0), 63);
        int ix = (int)roundf(((cx + 1.f) * 64.f - 1.f) * 0.5f);
        ix = min(max(ix, 0), 63);
        float ry = (cyq - (-1.f + (2 * iy + 1) / 64.f)) * 64.f;
        float rx = (cxq - (-1.f + (2 * ix + 1) / 64.f)) * 64.f;
        relY[c] = ry; relX[c] = rx;
        area[c] = fabsf(ry * rx) + 1e-9f;
        gofs[c] = ((b << 12) + (iy << 6) + ix) << 8;
    }
    const float inv = 1.f / (area[0] + area[1] + area[2] + area[3]);
    wgt[0] = area[3] * inv;  // diagonal swap (3,2,1,0)
    wgt[1] = area[2] * inv;
    wgt[2] = area[1] * inv;
    wgt[3] = area[0] * inv;

    const float* up = w1 + CC * HID + (lhi << 3);        // w1 row 64 (rel_y)
    const float* vp = w1 + (CC + 1) * HID + (lhi << 3);  // w1 row 65 (rel_x)
    const float* gp0 = G + gofs[0] + (lhi << 3);
    const float* gp1 = G + gofs[1] + (lhi << 3);
    const float* gp2 = G + gofs[2] + (lhi << 3);
    const float* gp3 = G + gofs[3] + (lhi << 3);
    const bf16x8* w2p = (const bf16x8*)W2F + l;

    f32x4 acc[4];
#pragma unroll
    for (int ng = 0; ng < 4; ++ng) acc[ng] = (f32x4){0.f, 0.f, 0.f, 0.f};

#pragma unroll
    for (int ks = 0; ks < 8; ++ks) {
        const int ko = ks * 32;          // compile-time: folds to imm offsets
        f32x4 ua = *(const f32x4*)(up + ko);
        f32x4 ub = *(const f32x4*)(up + ko + 4);
        f32x4 va = *(const f32x4*)(vp + ko);
        f32x4 vb = *(const f32x4*)(vp + ko + 4);
        f32x2 u2[4] = {{ua[0], ua[1]}, {ua[2], ua[3]}, {ub[0], ub[1]}, {ub[2], ub[3]}};
        f32x2 v2[4] = {{va[0], va[1]}, {va[2], va[3]}, {vb[0], vb[1]}, {vb[2], vb[3]}};
        f32x2 h[4] = {{0.f, 0.f}, {0.f, 0.f}, {0.f, 0.f}, {0.f, 0.f}};
        const float* gps[4] = {gp0, gp1, gp2, gp3};
#pragma unroll
        for (int c = 0; c < 4; ++c) {
            const float ry = relY[c], rx = relX[c], wc = wgt[c];
            f32x4 ga = *(const f32x4*)(gps[c] + ko);
            f32x4 gb = *(const f32x4*)(gps[c] + ko + 4);
            f32x2 g2[4] = {{ga[0], ga[1]}, {ga[2], ga[3]}, {gb[0], gb[1]}, {gb[2], gb[3]}};
#pragma unroll
            for (int e = 0; e < 4; ++e) {
                f32x2 t = g2[e] + ry * u2[e] + rx * v2[e];   // 2x pk_fma
                t[0] = fmaxf(t[0], 0.f);
                t[1] = fmaxf(t[1], 0.f);
                h[e] += wc * t;                               // pk_fma
            }
        }
        bf16x8 af;
#pragma unroll
        for (int e = 0; e < 4; ++e) {
            af[2 * e]     = (__bf16)h[e][0];
            af[2 * e + 1] = (__bf16)h[e][1];
        }
#pragma unroll
        for (int ng = 0; ng < 4; ++ng) {
            bf16x8 bfr = w2p[(ks * 4 + ng) * 64];
            acc[ng] = __builtin_amdgcn_mfma_f32_16x16x32_bf16(af, bfr, acc[ng], 0, 0, 0);
        }
    }

    // epilogue: in-wave transpose via small padded LDS, then coalesced stores
    __shared__ float lds[64 * 17];
#pragma unroll
    for (int ng = 0; ng < 4; ++ng) {
        const int o = (ng << 4) + dj;        // D-col = output channel
        const float bb = b2[o];
#pragma unroll
        for (int r = 0; r < 4; ++r) {
            const int p = (lhi << 2) + r;    // D-row = pixel index in strip
            lds[o * 17 + p] = acc[ng][r] + bb;
        }
    }
    __syncthreads();
#pragma unroll
    for (int ii = 0; ii < 16; ++ii) {
        const int o = (ii << 2) + lhi;
        out[((b * NOUT + o) * HOUT + i) * HOUT + j0 + dj] = lds[o * 17 + dj];
    }
}

extern "C" void kernel_launch(void* const* d_in, const int* in_sizes, int n_in,
                              void* d_out, int out_size, void* d_ws, size_t ws_size,
                              hipStream_t stream) {
    const float* res = (const float*)d_in[0];
    const float* w1  = (const float*)d_in[1];
    const float* b1  = (const float*)d_in[2];
    const float* w2  = (const float*)d_in[3];
    const float* b2  = (const float*)d_in[4];
    float* out = (float*)d_out;

    float*  G   = (float*)d_ws;                                // 2*4096*256 f32 = 8 MB
    __bf16* W2F = (__bf16*)((char*)d_ws + (size_t)(8u << 20)); // 32 KB

    k_gfeat<<<2 * 4096 / 8, 256, 0, stream>>>(res, w1, b1, G);
    k_w2f<<<64, 256, 0, stream>>>(w2, W2F);
    k_main<<<dim3(24, 384, 2), 64, 0, stream>>>(G, W2F, w1, b2, out);
}

// Round 3
// 57.143 us; speedup vs baseline: 2.2868x; 1.8440x over previous
//
#include <hip/hip_runtime.h>
#include <hip/hip_bf16.h>

typedef float f32x2 __attribute__((ext_vector_type(2)));
typedef float f32x4 __attribute__((ext_vector_type(4)));
typedef __bf16 bf16x8 __attribute__((ext_vector_type(8)));

#define CC   64
#define HID  256
#define NOUT 64
#define HOUT 384
#define CPAD 260            // f32 per staged cell (256 + 4 pad -> bank spread)
#define MAXCELL 10          // true bound is 2x4=8; margin
#define UVOFF (MAXCELL * CPAD)          // 2600
#define SMEMF 4352                      // max(2600+512, 4*1088) f32

__device__ __forceinline__ int corner_cell(float cq, float sh) {
    float c = cq + sh + 1e-6f;
    c = fminf(fmaxf(c, -1.f + 1e-6f), 1.f - 1e-6f);
    int i = (int)roundf(((c + 1.f) * 64.f - 1.f) * 0.5f);
    return min(max(i, 0), 63);
}

// ---- kernel A: G[cell][k] = b1[k] + sum_c res[b][c][iy][ix] * w1[c][k]
__global__ __launch_bounds__(256) void k_gfeat(const float* __restrict__ res,
                                               const float* __restrict__ w1,
                                               const float* __restrict__ b1,
                                               float* __restrict__ G) {
    const int cell0 = blockIdx.x * 8;
    const int tid = threadIdx.x;
    const int b = cell0 >> 12, iyix0 = cell0 & 4095;
    __shared__ float feat[8][65];
#pragma unroll
    for (int t = 0; t < 2; ++t) {
        int idx = t * 256 + tid;          // 0..511
        int c = idx >> 3, il = idx & 7;   // consecutive tid -> consecutive iyix (32B runs)
        feat[il][c] = res[((b * CC + c) << 12) + iyix0 + il];
    }
    __syncthreads();
    const int k = tid;
    float g[8];
    const float bk = b1[k];
#pragma unroll
    for (int cc = 0; cc < 8; ++cc) g[cc] = bk;
#pragma unroll
    for (int c = 0; c < CC; ++c) {
        const float w = w1[c * HID + k];
#pragma unroll
        for (int cc = 0; cc < 8; ++cc) g[cc] = fmaf(feat[cc][c], w, g[cc]);
    }
#pragma unroll
    for (int cc = 0; cc < 8; ++cc)
        G[((size_t)(cell0 + cc) << 8) + k] = g[cc];
}

// ---- kernel B: pre-shuffle w2 into MFMA B-fragment order, bf16
__global__ __launch_bounds__(256) void k_w2f(const float* __restrict__ w2,
                                             __bf16* __restrict__ W2F) {
    int f = blockIdx.x * 256 + threadIdx.x;   // 0..16383
    int e = f & 7;
    int l = (f >> 3) & 63;
    int grp = f >> 9;                 // kstep*4 + ng
    int kstep = grp >> 2, ng = grp & 3;
    int k = kstep * 32 + ((l >> 4) << 3) + e;
    int n = (ng << 4) + (l & 15);
    W2F[f] = (__bf16)w2[k * NOUT + n];
}

// ---- main: block = 4 waves = 4 px rows x 16 px cols. G cells staged in LDS.
// K-loop is pure LDS + VALU + MFMA; corner-dedup cuts nodes 4 -> ~2.3 avg.
__global__ __launch_bounds__(256, 4) void k_main(const float* __restrict__ G,
                                                 const __bf16* __restrict__ W2F,
                                                 const float* __restrict__ w1,
                                                 const float* __restrict__ b2,
                                                 float* __restrict__ out) {
    const int jt = blockIdx.x;        // 0..23
    const int it = blockIdx.y;        // 0..95
    const int b  = blockIdx.z;        // 0..1
    const int tid = threadIdx.x;
    const int wv = tid >> 6, l = tid & 63;
    const int lhi = l >> 4, dj = l & 15;
    const int i0 = it * 4, j0 = jt * 16;
    const int i = i0 + wv, j = j0 + dj;

    __shared__ float smem[SMEMF];

    // ---- uniform staged-cell ranges (monotone in coord -> exact bounds)
    const float S = 1.f / 384.f;
    const int r0 = corner_cell(-1.f + (2 * i0 + 1) / 384.f, -S);
    const int r1 = corner_cell(-1.f + (2 * (i0 + 3) + 1) / 384.f, +S);
    const int c0 = corner_cell(-1.f + (2 * j0 + 1) / 384.f, -S);
    const int c1 = corner_cell(-1.f + (2 * (j0 + 15) + 1) / 384.f, +S);
    const int nc = c1 - c0 + 1;
    const int ncell = (r1 - r0 + 1) * nc;

    // ---- stage cells (coalesced f32x4) + u/v rows of w1
    const float rcp_nc = 1.f / (float)nc;
#pragma unroll
    for (int t = 0; t < 3; ++t) {
        int idx = t * 256 + tid;                  // f32x4 slot = cell*64 + w4
        if (idx < (ncell << 6)) {
            int cell = idx >> 6, w4 = idx & 63;
            int cr = (int)((float)cell * rcp_nc); // exact for cell<=9, nc<=5
            int cc2 = cell - cr * nc;
            const float* src = G + (((size_t)((b << 12) + ((r0 + cr) << 6) + (c0 + cc2))) << 8) + (w4 << 2);
            *(f32x4*)(smem + cell * CPAD + (w4 << 2)) = *(const f32x4*)src;
        }
    }
    if (tid < 128)
        *(f32x4*)(smem + UVOFF + (tid << 2)) = *(const f32x4*)(w1 + CC * HID + (tid << 2));
    __syncthreads();

    // ---- per-pixel corner setup (dedup'd nodes)
    const float cyq = -1.f + (2 * i + 1) / 384.f;
    const float cxq = -1.f + (2 * j + 1) / 384.f;
    const int iym = corner_cell(cyq, -S), iyp = corner_cell(cyq, +S);
    const int ixm = corner_cell(cxq, -S), ixp = corner_cell(cxq, +S);
    const float ry0 = (cyq - (-1.f + (2 * iym + 1) / 64.f)) * 64.f;
    const float ry1 = (cyq - (-1.f + (2 * iyp + 1) / 64.f)) * 64.f;
    const float rx0 = (cxq - (-1.f + (2 * ixm + 1) / 64.f)) * 64.f;
    const float rx1 = (cxq - (-1.f + (2 * ixp + 1) / 64.f)) * 64.f;
    const bool ys = (iyp != iym), xs = (ixp != ixm);
    // corner order: c0(-,-) c1(-,+) c2(+,-) c3(+,+); area from node rels
    const float a0 = fabsf(ry0 * rx0) + 1e-9f;
    const float a1 = fabsf(ry0 * (xs ? rx1 : rx0)) + 1e-9f;
    const float a2 = fabsf((ys ? ry1 : ry0) * rx0) + 1e-9f;
    const float a3 = fabsf((ys ? ry1 : ry0) * (xs ? rx1 : rx0)) + 1e-9f;
    const float inv = 1.f / (a0 + a1 + a2 + a3);
    const float g0w = a3 * inv, g1w = a2 * inv, g2w = a1 * inv, g3w = a0 * inv;
    float W00 = g0w, W01 = 0.f, W10 = 0.f, W11 = 0.f;
    if (xs) W01 += g1w; else W00 += g1w;
    if (ys) W10 += g2w; else W00 += g2w;
    if (ys && xs) W11 += g3w;
    else if (ys)  W10 += g3w;
    else if (xs)  W01 += g3w;
    else          W00 += g3w;

    const int lo = lhi << 3;                      // f32 chunk offset for this lane
    const float* base00 = smem + ((iym - r0) * nc + (ixm - c0)) * CPAD + lo;
    const float* base01 = smem + ((iym - r0) * nc + (ixp - c0)) * CPAD + lo;
    const float* base10 = smem + ((iyp - r0) * nc + (ixm - c0)) * CPAD + lo;
    const float* base11 = smem + ((iyp - r0) * nc + (ixp - c0)) * CPAD + lo;
    const float* uL = smem + UVOFF + lo;
    const float* vL = smem + UVOFF + 256 + lo;
    const bf16x8* w2p = (const bf16x8*)W2F + l;

    f32x4 acc[4];
#pragma unroll
    for (int ng = 0; ng < 4; ++ng) acc[ng] = (f32x4){0.f, 0.f, 0.f, 0.f};

#define NODE(bp, ry, rx, W) {                                              \
        f32x4 gA = *(const f32x4*)((bp) + ko);                             \
        f32x4 gB = *(const f32x4*)((bp) + ko + 4);                         \
        f32x2 t;                                                           \
        t = (f32x2){gA[0], gA[1]} + (ry) * u0 + (rx) * v0;                 \
        t = __builtin_elementwise_max(t, (f32x2){0.f, 0.f});               \
        h0 += (W) * t;                                                     \
        t = (f32x2){gA[2], gA[3]} + (ry) * u1 + (rx) * v1;                 \
        t = __builtin_elementwise_max(t, (f32x2){0.f, 0.f});               \
        h1 += (W) * t;                                                     \
        t = (f32x2){gB[0], gB[1]} + (ry) * u2 + (rx) * v2;                 \
        t = __builtin_elementwise_max(t, (f32x2){0.f, 0.f});               \
        h2 += (W) * t;                                                     \
        t = (f32x2){gB[2], gB[3]} + (ry) * u3 + (rx) * v3;                 \
        t = __builtin_elementwise_max(t, (f32x2){0.f, 0.f});               \
        h3 += (W) * t; }

#pragma unroll
    for (int ks = 0; ks < 8; ++ks) {
        const int ko = ks * 32;
        f32x4 uA = *(const f32x4*)(uL + ko), uB = *(const f32x4*)(uL + ko + 4);
        f32x4 vA = *(const f32x4*)(vL + ko), vB = *(const f32x4*)(vL + ko + 4);
        const f32x2 u0 = {uA[0], uA[1]}, u1 = {uA[2], uA[3]};
        const f32x2 u2 = {uB[0], uB[1]}, u3 = {uB[2], uB[3]};
        const f32x2 v0 = {vA[0], vA[1]}, v1 = {vA[2], vA[3]};
        const f32x2 v2 = {vB[0], vB[1]}, v3 = {vB[2], vB[3]};
        f32x2 h0 = {0.f, 0.f}, h1 = {0.f, 0.f}, h2 = {0.f, 0.f}, h3 = {0.f, 0.f};
        NODE(base00, ry0, rx0, W00);
        if (xs) NODE(base01, ry0, rx1, W01);          // per-lane mask
        if (ys) {                                     // wave-uniform skip
            NODE(base10, ry1, rx0, W10);
            if (xs) NODE(base11, ry1, rx1, W11);
        }
        bf16x8 af;
        af[0] = (__bf16)h0[0]; af[1] = (__bf16)h0[1];
        af[2] = (__bf16)h1[0]; af[3] = (__bf16)h1[1];
        af[4] = (__bf16)h2[0]; af[5] = (__bf16)h2[1];
        af[6] = (__bf16)h3[0]; af[7] = (__bf16)h3[1];
#pragma unroll
        for (int ng = 0; ng < 4; ++ng)
            acc[ng] = __builtin_amdgcn_mfma_f32_16x16x32_bf16(af, w2p[(ks * 4 + ng) * 64], acc[ng], 0, 0, 0);
    }
#undef NODE

    // ---- epilogue: reuse smem (barrier!), per-wave transpose, coalesced stores
    __syncthreads();
    float* epi = smem + wv * 1088;
#pragma unroll
    for (int ng = 0; ng < 4; ++ng) {
        const int o = (ng << 4) + dj;
        const float bb = b2[o];
#pragma unroll
        for (int r = 0; r < 4; ++r)
            epi[o * 17 + ((lhi << 2) + r)] = acc[ng][r] + bb;
    }
#pragma unroll
    for (int ii = 0; ii < 16; ++ii) {
        const int o = (ii << 2) + lhi;
        out[(((size_t)b * NOUT + o) * HOUT + i) * HOUT + j0 + dj] = epi[o * 17 + dj];
    }
}

extern "C" void kernel_launch(void* const* d_in, const int* in_sizes, int n_in,
                              void* d_out, int out_size, void* d_ws, size_t ws_size,
                              hipStream_t stream) {
    const float* res = (const float*)d_in[0];
    const float* w1  = (const float*)d_in[1];
    const float* b1  = (const float*)d_in[2];
    const float* w2  = (const float*)d_in[3];
    const float* b2  = (const float*)d_in[4];
    float* out = (float*)d_out;

    float*  G   = (float*)d_ws;                                // 8 MB
    __bf16* W2F = (__bf16*)((char*)d_ws + (size_t)(8u << 20)); // 32 KB

    k_gfeat<<<2 * 4096 / 8, 256, 0, stream>>>(res, w1, b1, G);
    k_w2f<<<64, 256, 0, stream>>>(w2, W2F);
    k_main<<<dim3(24, 96, 2), 256, 0, stream>>>(G, W2F, w1, b2, out);
}

// Round 4
// 50.310 us; speedup vs baseline: 2.5974x; 1.1358x over previous
//
#include <hip/hip_runtime.h>
#include <hip/hip_bf16.h>

typedef float f32x4 __attribute__((ext_vector_type(4)));
typedef _Float16 f16x2 __attribute__((ext_vector_type(2)));
typedef _Float16 f16x8 __attribute__((ext_vector_type(8)));

#define CC   64
#define HID  256
#define NOUT 64
#define HOUT 384
#define MAXCELL 8           // strip tile touches <=2 cell-rows x 4 cell-cols
#define CELLB 512           // bytes per staged f16 cell (256 * 2B)
#define UVB  (MAXCELL * CELLB)   // uv base byte offset in LDS

__device__ __forceinline__ int corner_cell(float cq, float sh) {
    float c = cq + sh + 1e-6f;
    c = fminf(fmaxf(c, -1.f + 1e-6f), 1.f - 1e-6f);
    int i = (int)roundf(((c + 1.f) * 64.f - 1.f) * 0.5f);
    return min(max(i, 0), 63);
}

// ---- kernel A: G[cell][k] = f16( b1[k] + sum_c res[b][c][iy][ix] * w1[c][k] )
__global__ __launch_bounds__(256) void k_gfeat(const float* __restrict__ res,
                                               const float* __restrict__ w1,
                                               const float* __restrict__ b1,
                                               _Float16* __restrict__ G) {
    const int cell0 = blockIdx.x * 8;
    const int tid = threadIdx.x;
    const int b = cell0 >> 12, iyix0 = cell0 & 4095;
    __shared__ float feat[8][65];
#pragma unroll
    for (int t = 0; t < 2; ++t) {
        int idx = t * 256 + tid;          // 0..511
        int c = idx >> 3, il = idx & 7;   // consecutive tid -> consecutive iyix
        feat[il][c] = res[((b * CC + c) << 12) + iyix0 + il];
    }
    __syncthreads();
    const int k = tid;
    float g[8];
    const float bk = b1[k];
#pragma unroll
    for (int cc = 0; cc < 8; ++cc) g[cc] = bk;
#pragma unroll
    for (int c = 0; c < CC; ++c) {
        const float w = w1[c * HID + k];
#pragma unroll
        for (int cc = 0; cc < 8; ++cc) g[cc] = fmaf(feat[cc][c], w, g[cc]);
    }
#pragma unroll
    for (int cc = 0; cc < 8; ++cc)
        G[((size_t)(cell0 + cc) << 8) + k] = (_Float16)g[cc];
}

// ---- kernel B: pre-shuffle w2 into f16 MFMA B-fragment order
__global__ __launch_bounds__(256) void k_w2f(const float* __restrict__ w2,
                                             _Float16* __restrict__ W2F) {
    int f = blockIdx.x * 256 + threadIdx.x;   // 0..16383
    int e = f & 7;
    int l = (f >> 3) & 63;
    int grp = f >> 9;                 // kstep*4 + ng
    int kstep = grp >> 2, ng = grp & 3;
    int k = kstep * 32 + ((l >> 4) << 3) + e;
    int n = (ng << 4) + (l & 15);
    W2F[f] = (_Float16)w2[k * NOUT + n];
}

// ---- main: 4 waves = 4 px rows x 16 px cols. f16 cells+uv in LDS, f16 pk math,
// f16 MFMA, direct global stores. Single barrier.
__global__ __launch_bounds__(256, 6) void k_main(const _Float16* __restrict__ G,
                                                 const _Float16* __restrict__ W2F,
                                                 const float* __restrict__ w1,
                                                 const float* __restrict__ b2,
                                                 float* __restrict__ out) {
    const int jt = blockIdx.x;        // 0..23
    const int it = blockIdx.y;        // 0..95
    const int b  = blockIdx.z;        // 0..1
    const int tid = threadIdx.x;
    const int wv = tid >> 6, l = tid & 63;
    const int lhi = l >> 4, dj = l & 15;
    const int i0 = it * 4, j0 = jt * 16;
    const int i = i0 + wv, j = j0 + dj;

    __shared__ char smem[MAXCELL * CELLB + 1024];   // cells + u/v (f16)

    // ---- uniform staged-cell ranges
    const float S = 1.f / 384.f;
    const int r0 = corner_cell(-1.f + (2 * i0 + 1) / 384.f, -S);
    const int r1 = corner_cell(-1.f + (2 * (i0 + 3) + 1) / 384.f, +S);
    const int c0 = corner_cell(-1.f + (2 * j0 + 1) / 384.f, -S);
    const int c1 = corner_cell(-1.f + (2 * (j0 + 15) + 1) / 384.f, +S);
    const int nc = c1 - c0 + 1;
    const int ncell = (r1 - r0 + 1) * nc;

    // ---- stage cells (f16, 16B chunks) + u/v rows of w1 (cvt f32->f16)
    {
        int cell = tid >> 5, c16 = tid & 31;      // one 16B chunk per thread
        if (cell < ncell) {
            const float rcp_nc = 1.f / (float)nc;
            int cr = (int)((float)cell * rcp_nc);
            int cc2 = cell - cr * nc;
            const _Float16* src = G + (((size_t)((b << 12) + ((r0 + cr) << 6) + (c0 + cc2))) << 8) + (c16 << 3);
            *(f32x4*)(smem + cell * CELLB + (c16 << 4)) = *(const f32x4*)src;
        }
        if (tid < 128) {
            f32x4 w4 = *(const f32x4*)(w1 + CC * HID + (tid << 2));
            f16x2 lo = {(_Float16)w4[0], (_Float16)w4[1]};
            f16x2 hi = {(_Float16)w4[2], (_Float16)w4[3]};
            *(f16x2*)(smem + UVB + (tid << 3)) = lo;
            *(f16x2*)(smem + UVB + (tid << 3) + 4) = hi;
        }
    }
    __syncthreads();

    // ---- per-pixel corner setup (f32 path identical to R2, then cast)
    const float cyq = -1.f + (2 * i + 1) / 384.f;
    const float cxq = -1.f + (2 * j + 1) / 384.f;
    const int iym = corner_cell(cyq, -S), iyp = corner_cell(cyq, +S);
    const int ixm = corner_cell(cxq, -S), ixp = corner_cell(cxq, +S);
    const float ry0 = (cyq - (-1.f + (2 * iym + 1) / 64.f)) * 64.f;
    const float ry1 = (cyq - (-1.f + (2 * iyp + 1) / 64.f)) * 64.f;
    const float rx0 = (cxq - (-1.f + (2 * ixm + 1) / 64.f)) * 64.f;
    const float rx1 = (cxq - (-1.f + (2 * ixp + 1) / 64.f)) * 64.f;
    const bool ys = (iyp != iym), xs = (ixp != ixm);
    const float a0 = fabsf(ry0 * rx0) + 1e-9f;
    const float a1 = fabsf(ry0 * (xs ? rx1 : rx0)) + 1e-9f;
    const float a2 = fabsf((ys ? ry1 : ry0) * rx0) + 1e-9f;
    const float a3 = fabsf((ys ? ry1 : ry0) * (xs ? rx1 : rx0)) + 1e-9f;
    const float inv = 1.f / (a0 + a1 + a2 + a3);
    const float g0w = a3 * inv, g1w = a2 * inv, g2w = a1 * inv, g3w = a0 * inv;
    float W00 = g0w, W01 = 0.f, W10 = 0.f, W11 = 0.f;
    if (xs) W01 += g1w; else W00 += g1w;
    if (ys) W10 += g2w; else W00 += g2w;
    if (ys && xs) W11 += g3w;
    else if (ys)  W10 += g3w;
    else if (xs)  W01 += g3w;
    else          W00 += g3w;

#define DUP2(x) (f16x2){(_Float16)(x), (_Float16)(x)}
    const f16x2 ry0h = DUP2(ry0), ry1h = DUP2(ry1);
    const f16x2 rx0h = DUP2(rx0), rx1h = DUP2(rx1);
    const f16x2 W00h = DUP2(W00), W01h = DUP2(W01);
    const f16x2 W10h = DUP2(W10), W11h = DUP2(W11);

    const int lo16 = lhi << 4;     // byte offset of lane's k-chunk within a cell-ks row
    const char* cell00 = smem + ((iym - r0) * nc + (ixm - c0)) * CELLB + lo16;
    const char* cell01 = smem + ((iym - r0) * nc + (ixp - c0)) * CELLB + lo16;
    const char* cell10 = smem + ((iyp - r0) * nc + (ixm - c0)) * CELLB + lo16;
    const char* cell11 = smem + ((iyp - r0) * nc + (ixp - c0)) * CELLB + lo16;
    const char* uvp = smem + UVB + lo16;
    const f16x8* w2p = (const f16x8*)W2F + l;

    f32x4 acc[4];
#pragma unroll
    for (int ng = 0; ng < 4; ++ng) acc[ng] = (f32x4){0.f, 0.f, 0.f, 0.f};

#define NODE(cp, ryh, rxh, Wh) {                                           \
        f16x8 gv = *(const f16x8*)((cp) + ko);                             \
        f16x2 g2;                                                          \
        _Pragma("unroll")                                                  \
        for (int e = 0; e < 4; ++e) {                                      \
            g2[0] = gv[2*e]; g2[1] = gv[2*e+1];                            \
            f16x2 t = g2 + (ryh) * uu[e] + (rxh) * vv[e];                  \
            t = __builtin_elementwise_max(t, (f16x2){(_Float16)0.f, (_Float16)0.f}); \
            h[e] += (Wh) * t;                                              \
        } }

#pragma unroll
    for (int ks = 0; ks < 8; ++ks) {
        const int ko = ks * 64;                      // bytes per ks across a cell
        f16x8 uraw = *(const f16x8*)(uvp + ko);
        f16x8 vraw = *(const f16x8*)(uvp + 512 + ko);
        f16x2 uu[4], vv[4];
#pragma unroll
        for (int e = 0; e < 4; ++e) {
            uu[e][0] = uraw[2*e]; uu[e][1] = uraw[2*e+1];
            vv[e][0] = vraw[2*e]; vv[e][1] = vraw[2*e+1];
        }
        f16x2 h[4] = {};
        NODE(cell00, ry0h, rx0h, W00h);
        NODE(cell01, ry0h, rx1h, W01h);
        if (ys) {
            NODE(cell10, ry1h, rx0h, W10h);
            NODE(cell11, ry1h, rx1h, W11h);
        }
        f16x8 af;
#pragma unroll
        for (int e = 0; e < 4; ++e) { af[2*e] = h[e][0]; af[2*e+1] = h[e][1]; }
#pragma unroll
        for (int ng = 0; ng < 4; ++ng)
            acc[ng] = __builtin_amdgcn_mfma_f32_16x16x32_f16(af, w2p[(ks * 4 + ng) * 64], acc[ng], 0, 0, 0);
    }
#undef NODE

    // ---- epilogue: direct stores (D row = pixel, D col = out channel)
#pragma unroll
    for (int ng = 0; ng < 4; ++ng) {
        const int o = (ng << 4) + dj;
        const float bb = b2[o];
        float* op = out + (((size_t)b * NOUT + o) * HOUT + i) * HOUT + j0 + (lhi << 2);
#pragma unroll
        for (int r = 0; r < 4; ++r)
            op[r] = acc[ng][r] + bb;
    }
}

extern "C" void kernel_launch(void* const* d_in, const int* in_sizes, int n_in,
                              void* d_out, int out_size, void* d_ws, size_t ws_size,
                              hipStream_t stream) {
    const float* res = (const float*)d_in[0];
    const float* w1  = (const float*)d_in[1];
    const float* b1  = (const float*)d_in[2];
    const float* w2  = (const float*)d_in[3];
    const float* b2  = (const float*)d_in[4];
    float* out = (float*)d_out;

    _Float16* G   = (_Float16*)d_ws;                                // 4 MB
    _Float16* W2F = (_Float16*)((char*)d_ws + (size_t)(8u << 20));  // 32 KB

    k_gfeat<<<2 * 4096 / 8, 256, 0, stream>>>(res, w1, b1, G);
    k_w2f<<<64, 256, 0, stream>>>(w2, W2F);
    k_main<<<dim3(24, 96, 2), 256, 0, stream>>>(G, W2F, w1, b2, out);
}

// Round 5
// 48.393 us; speedup vs baseline: 2.7002x; 1.0396x over previous
//
#include <hip/hip_runtime.h>
#include <hip/hip_bf16.h>

typedef float f32x4 __attribute__((ext_vector_type(4)));
typedef _Float16 f16x2 __attribute__((ext_vector_type(2)));
typedef _Float16 f16x8 __attribute__((ext_vector_type(8)));

#define CC   64
#define HID  256
#define NOUT 64
#define HOUT 384
#define MAXCELL 8
#define CELLB 544                 // 512 data + 32 pad: cells start 8 banks apart
#define UVB  (MAXCELL * CELLB)    // 4352
#define W2B  (UVB + 1024)         // 5376
#define SMEMB (W2B + 32768)       // 38144 bytes -> 4 blocks/CU

__device__ __forceinline__ int corner_cell(float cq, float sh) {
    float c = cq + sh + 1e-6f;
    c = fminf(fmaxf(c, -1.f + 1e-6f), 1.f - 1e-6f);
    int i = (int)roundf(((c + 1.f) * 64.f - 1.f) * 0.5f);
    return min(max(i, 0), 63);
}

// ---- kernel A: G[cell][k] = f16( b1[k] + sum_c res[b][c][iy][ix] * w1[c][k] )
__global__ __launch_bounds__(256) void k_gfeat(const float* __restrict__ res,
                                               const float* __restrict__ w1,
                                               const float* __restrict__ b1,
                                               _Float16* __restrict__ G) {
    const int cell0 = blockIdx.x * 8;
    const int tid = threadIdx.x;
    const int b = cell0 >> 12, iyix0 = cell0 & 4095;
    __shared__ float feat[8][65];
#pragma unroll
    for (int t = 0; t < 2; ++t) {
        int idx = t * 256 + tid;
        int c = idx >> 3, il = idx & 7;
        feat[il][c] = res[((b * CC + c) << 12) + iyix0 + il];
    }
    __syncthreads();
    const int k = tid;
    float g[8];
    const float bk = b1[k];
#pragma unroll
    for (int cc = 0; cc < 8; ++cc) g[cc] = bk;
#pragma unroll
    for (int c = 0; c < CC; ++c) {
        const float w = w1[c * HID + k];
#pragma unroll
        for (int cc = 0; cc < 8; ++cc) g[cc] = fmaf(feat[cc][c], w, g[cc]);
    }
#pragma unroll
    for (int cc = 0; cc < 8; ++cc)
        G[((size_t)(cell0 + cc) << 8) + k] = (_Float16)g[cc];
}

// ---- kernel B: pre-shuffle w2 into f16 MFMA B-fragment order
__global__ __launch_bounds__(256) void k_w2f(const float* __restrict__ w2,
                                             _Float16* __restrict__ W2F) {
    int f = blockIdx.x * 256 + threadIdx.x;   // 0..16383
    int e = f & 7;
    int l = (f >> 3) & 63;
    int grp = f >> 9;
    int kstep = grp >> 2, ng = grp & 3;
    int k = kstep * 32 + ((l >> 4) << 3) + e;
    int n = (ng << 4) + (l & 15);
    W2F[f] = (_Float16)w2[k * NOUT + n];
}

// ---- main: 4 waves = 4 px rows x 16 px cols. Cells+uv+W2F all in LDS:
// K-loop has ZERO VMEM. Direct global stores.
__global__ __launch_bounds__(256, 4) void k_main(const _Float16* __restrict__ G,
                                                 const _Float16* __restrict__ W2F,
                                                 const float* __restrict__ w1,
                                                 const float* __restrict__ b2,
                                                 float* __restrict__ out) {
    const int jt = blockIdx.x;
    const int it = blockIdx.y;
    const int b  = blockIdx.z;
    const int tid = threadIdx.x;
    const int wv = tid >> 6, l = tid & 63;
    const int lhi = l >> 4, dj = l & 15;
    const int i0 = it * 4, j0 = jt * 16;
    const int i = i0 + wv, j = j0 + dj;

    __shared__ char smem[SMEMB];

    const float S = 1.f / 384.f;
    const int r0 = corner_cell(-1.f + (2 * i0 + 1) / 384.f, -S);
    const int r1 = corner_cell(-1.f + (2 * (i0 + 3) + 1) / 384.f, +S);
    const int c0 = corner_cell(-1.f + (2 * j0 + 1) / 384.f, -S);
    const int c1 = corner_cell(-1.f + (2 * (j0 + 15) + 1) / 384.f, +S);
    const int nc = c1 - c0 + 1;
    const int ncell = (r1 - r0 + 1) * nc;

    // ---- stage: cells (f16), uv (cvt f32->f16), W2F (32 KB, 16B/thread x8)
    {
        int cell = tid >> 5, c16 = tid & 31;
        if (cell < ncell) {
            const float rcp_nc = 1.f / (float)nc;
            int cr = (int)((float)cell * rcp_nc);
            int cc2 = cell - cr * nc;
            const _Float16* src = G + (((size_t)((b << 12) + ((r0 + cr) << 6) + (c0 + cc2))) << 8) + (c16 << 3);
            *(f32x4*)(smem + cell * CELLB + (c16 << 4)) = *(const f32x4*)src;
        }
        if (tid < 128) {
            f32x4 w4 = *(const f32x4*)(w1 + CC * HID + (tid << 2));
            f16x2 lo = {(_Float16)w4[0], (_Float16)w4[1]};
            f16x2 hi = {(_Float16)w4[2], (_Float16)w4[3]};
            *(f16x2*)(smem + UVB + (tid << 3)) = lo;
            *(f16x2*)(smem + UVB + (tid << 3) + 4) = hi;
        }
        const f32x4* w2g = (const f32x4*)W2F;
#pragma unroll
        for (int t = 0; t < 8; ++t)
            *(f32x4*)(smem + W2B + ((t * 256 + tid) << 4)) = w2g[t * 256 + tid];
    }
    __syncthreads();

    // ---- per-pixel corner setup
    const float cyq = -1.f + (2 * i + 1) / 384.f;
    const float cxq = -1.f + (2 * j + 1) / 384.f;
    const int iym = corner_cell(cyq, -S), iyp = corner_cell(cyq, +S);
    const int ixm = corner_cell(cxq, -S), ixp = corner_cell(cxq, +S);
    const float ry0 = (cyq - (-1.f + (2 * iym + 1) / 64.f)) * 64.f;
    const float ry1 = (cyq - (-1.f + (2 * iyp + 1) / 64.f)) * 64.f;
    const float rx0 = (cxq - (-1.f + (2 * ixm + 1) / 64.f)) * 64.f;
    const float rx1 = (cxq - (-1.f + (2 * ixp + 1) / 64.f)) * 64.f;
    const bool ys = (iyp != iym), xs = (ixp != ixm);
    const float a0 = fabsf(ry0 * rx0) + 1e-9f;
    const float a1 = fabsf(ry0 * (xs ? rx1 : rx0)) + 1e-9f;
    const float a2 = fabsf((ys ? ry1 : ry0) * rx0) + 1e-9f;
    const float a3 = fabsf((ys ? ry1 : ry0) * (xs ? rx1 : rx0)) + 1e-9f;
    const float inv = 1.f / (a0 + a1 + a2 + a3);
    const float g0w = a3 * inv, g1w = a2 * inv, g2w = a1 * inv, g3w = a0 * inv;
    float W00 = g0w, W01 = 0.f, W10 = 0.f, W11 = 0.f;
    if (xs) W01 += g1w; else W00 += g1w;
    if (ys) W10 += g2w; else W00 += g2w;
    if (ys && xs) W11 += g3w;
    else if (ys)  W10 += g3w;
    else if (xs)  W01 += g3w;
    else          W00 += g3w;

#define DUP2(x) (f16x2){(_Float16)(x), (_Float16)(x)}
    const f16x2 ry0h = DUP2(ry0), ry1h = DUP2(ry1);
    const f16x2 rx0h = DUP2(rx0), rx1h = DUP2(rx1);
    const f16x2 W00h = DUP2(W00), W01h = DUP2(W01);
    const f16x2 W10h = DUP2(W10), W11h = DUP2(W11);

    const int lo16 = lhi << 4;
    const char* cell00 = smem + ((iym - r0) * nc + (ixm - c0)) * CELLB + lo16;
    const char* cell01 = smem + ((iym - r0) * nc + (ixp - c0)) * CELLB + lo16;
    const char* cell10 = smem + ((iyp - r0) * nc + (ixm - c0)) * CELLB + lo16;
    const char* cell11 = smem + ((iyp - r0) * nc + (ixp - c0)) * CELLB + lo16;
    const char* uvp = smem + UVB + lo16;
    const f16x8* w2l = (const f16x8*)(smem + W2B) + l;

    f32x4 acc[4];
#pragma unroll
    for (int ng = 0; ng < 4; ++ng) acc[ng] = (f32x4){0.f, 0.f, 0.f, 0.f};

#define NODE(cp, ryh, rxh, Wh) {                                           \
        f16x8 gv = *(const f16x8*)((cp) + ko);                             \
        f16x2 g2;                                                          \
        _Pragma("unroll")                                                  \
        for (int e = 0; e < 4; ++e) {                                      \
            g2[0] = gv[2*e]; g2[1] = gv[2*e+1];                            \
            f16x2 t = g2 + (ryh) * uu[e] + (rxh) * vv[e];                  \
            t = __builtin_elementwise_max(t, (f16x2){(_Float16)0.f, (_Float16)0.f}); \
            h[e] += (Wh) * t;                                              \
        } }

#pragma unroll
    for (int ks = 0; ks < 8; ++ks) {
        const int ko = ks * 64;
        f16x8 uraw = *(const f16x8*)(uvp + ko);
        f16x8 vraw = *(const f16x8*)(uvp + 512 + ko);
        f16x2 uu[4], vv[4];
#pragma unroll
        for (int e = 0; e < 4; ++e) {
            uu[e][0] = uraw[2*e]; uu[e][1] = uraw[2*e+1];
            vv[e][0] = vraw[2*e]; vv[e][1] = vraw[2*e+1];
        }
        f16x2 h[4] = {};
        NODE(cell00, ry0h, rx0h, W00h);
        NODE(cell01, ry0h, rx1h, W01h);
        if (ys) {
            NODE(cell10, ry1h, rx0h, W10h);
            NODE(cell11, ry1h, rx1h, W11h);
        }
        f16x8 af;
#pragma unroll
        for (int e = 0; e < 4; ++e) { af[2*e] = h[e][0]; af[2*e+1] = h[e][1]; }
#pragma unroll
        for (int ng = 0; ng < 4; ++ng)
            acc[ng] = __builtin_amdgcn_mfma_f32_16x16x32_f16(af, w2l[(ks * 4 + ng) * 64], acc[ng], 0, 0, 0);
    }
#undef NODE

    // ---- epilogue: direct stores
#pragma unroll
    for (int ng = 0; ng < 4; ++ng) {
        const int o = (ng << 4) + dj;
        const float bb = b2[o];
        float* op = out + (((size_t)b * NOUT + o) * HOUT + i) * HOUT + j0 + (lhi << 2);
#pragma unroll
        for (int r = 0; r < 4; ++r)
            op[r] = acc[ng][r] + bb;
    }
}

extern "C" void kernel_launch(void* const* d_in, const int* in_sizes, int n_in,
                              void* d_out, int out_size, void* d_ws, size_t ws_size,
                              hipStream_t stream) {
    const float* res = (const float*)d_in[0];
    const float* w1  = (const float*)d_in[1];
    const float* b1  = (const float*)d_in[2];
    const float* w2  = (const float*)d_in[3];
    const float* b2  = (const float*)d_in[4];
    float* out = (float*)d_out;

    _Float16* G   = (_Float16*)d_ws;                                // 4 MB
    _Float16* W2F = (_Float16*)((char*)d_ws + (size_t)(8u << 20));  // 32 KB

    k_gfeat<<<2 * 4096 / 8, 256, 0, stream>>>(res, w1, b1, G);
    k_w2f<<<64, 256, 0, stream>>>(w2, W2F);
    k_main<<<dim3(24, 96, 2), 256, 0, stream>>>(G, W2F, w1, b2, out);
}

// Round 6
// 46.233 us; speedup vs baseline: 2.8263x; 1.0467x over previous
//
#include <hip/hip_runtime.h>
#include <hip/hip_bf16.h>

typedef float f32x4 __attribute__((ext_vector_type(4)));
typedef _Float16 f16x2 __attribute__((ext_vector_type(2)));
typedef _Float16 f16x8 __attribute__((ext_vector_type(8)));

#define CC   64
#define HID  256
#define NOUT 64
#define HOUT 384
#define MAXCELL 8
#define CELLB 544                 // 512 data + 32 pad: cells start 8 banks apart
#define UVB  (MAXCELL * CELLB)    // 4352
#define W2B  (UVB + 1024)         // 5376
#define SMEMB (W2B + 32768)       // 38144 bytes -> 4 blocks/CU

__device__ __forceinline__ int corner_cell(float cq, float sh) {
    float c = cq + sh + 1e-6f;
    c = fminf(fmaxf(c, -1.f + 1e-6f), 1.f - 1e-6f);
    int i = (int)roundf(((c + 1.f) * 64.f - 1.f) * 0.5f);
    return min(max(i, 0), 63);
}

// ---- k_prep: shuffle w2 -> W2F frags, w1[0:64] -> W1F frags, w1[64:66] -> UVH f16
__global__ __launch_bounds__(256) void k_prep(const float* __restrict__ w1,
                                              const float* __restrict__ w2,
                                              _Float16* __restrict__ W2F,
                                              _Float16* __restrict__ W1F,
                                              _Float16* __restrict__ UVH) {
    int idx = blockIdx.x * 256 + threadIdx.x;
    if (idx < 16384) {                         // W2F: f = ((ks*4+ng)*64+l)*8+e
        int f = idx, e = f & 7, l = (f >> 3) & 63, grp = f >> 9;
        int ks = grp >> 2, ng = grp & 3;
        int k = ks * 32 + ((l >> 4) << 3) + e;
        int n = (ng << 4) + (l & 15);
        W2F[f] = (_Float16)w2[k * NOUT + n];
    } else if (idx < 32768) {                  // W1F: f = ((ks*16+ng)*64+l)*8+e
        int f = idx - 16384, e = f & 7, l = (f >> 3) & 63, grp = f >> 9;
        int ks = grp >> 4, ng = grp & 15;
        int k = ks * 32 + ((l >> 4) << 3) + e;
        int n = (ng << 4) + (l & 15);
        W1F[f] = (_Float16)w1[k * HID + n];
    } else if (idx < 32768 + 512) {            // UVH: u[256] then v[256]
        int f = idx - 32768;
        UVH[f] = (_Float16)w1[(CC + (f >> 8)) * HID + (f & 255)];
    }
}

// ---- k_gfeat (MFMA): G[cell][n] = b1[n] + sum_c res_f16[cell][c] * w1_f16[c][n]
// 256 blocks x 32 cells; A via LDS transpose; B = W1F frags (L1-hot); b1 in acc-init.
__global__ __launch_bounds__(256) void k_gfeat(const float* __restrict__ res,
                                               const _Float16* __restrict__ W1F,
                                               const float* __restrict__ b1,
                                               _Float16* __restrict__ G) {
    const int cell0 = blockIdx.x * 32;
    const int b = cell0 >> 12, iyix0 = cell0 & 4095;
    const int tid = threadIdx.x;
    __shared__ _Float16 lds_a[32][72];     // [cell][c], row 144 B
    __shared__ _Float16 lds_d[32][264];    // [cell][n], row 528 B

    {   // stage res -> lds_a (f32->f16, transpose)
        int c = tid >> 2, cs = (tid & 3) * 8;
        const float* src = res + (((b * CC + c) << 12) + iyix0 + cs);
        f32x4 r0 = *(const f32x4*)src;
        f32x4 r1 = *(const f32x4*)(src + 4);
#pragma unroll
        for (int e = 0; e < 4; ++e) lds_a[cs + e][c] = (_Float16)r0[e];
#pragma unroll
        for (int e = 0; e < 4; ++e) lds_a[cs + 4 + e][c] = (_Float16)r1[e];
    }
    __syncthreads();

    const int wv = tid >> 6, l = tid & 63, lhi = l >> 4, dj = l & 15;
    const int crow = (wv & 1) * 16;        // wave's 16-cell base
    const int nh = (wv >> 1) * 8;          // wave's ng half: [nh, nh+8)

    f32x4 acc[8];
#pragma unroll
    for (int q = 0; q < 8; ++q) {
        float bb = b1[(nh + q) * 16 + dj];
        acc[q] = (f32x4){bb, bb, bb, bb};  // C[row][col] = b1[col]
    }
#pragma unroll
    for (int ks = 0; ks < 2; ++ks) {
        f16x8 afr = *(const f16x8*)&lds_a[crow + dj][ks * 32 + lhi * 8];
#pragma unroll
        for (int q = 0; q < 8; ++q) {
            f16x8 bfr = *(const f16x8*)(W1F + (((ks * 16 + nh + q) * 64 + l) << 3));
            acc[q] = __builtin_amdgcn_mfma_f32_16x16x32_f16(afr, bfr, acc[q], 0, 0, 0);
        }
    }
    // D -> lds_d
#pragma unroll
    for (int q = 0; q < 8; ++q) {
        int n = (nh + q) * 16 + dj;
#pragma unroll
        for (int r = 0; r < 4; ++r)
            lds_d[crow + lhi * 4 + r][n] = (_Float16)acc[q][r];
    }
    __syncthreads();
    {   // out: 32 cells x 256 f16, coalesced dwordx4
        int cell = tid >> 3, ch = (tid & 7) * 32;
        _Float16* dst = G + (((size_t)(cell0 + cell)) << 8) + ch;
#pragma unroll
        for (int r = 0; r < 4; ++r)
            *(f32x4*)(dst + r * 8) = *(const f32x4*)&lds_d[cell][ch + r * 8];
    }
}

// ---- main: 4 waves = 4 px rows x 16 px cols. Cells+uv+W2F all in LDS:
// K-loop has ZERO VMEM. Direct global stores.
__global__ __launch_bounds__(256, 4) void k_main(const _Float16* __restrict__ G,
                                                 const _Float16* __restrict__ W2F,
                                                 const _Float16* __restrict__ UVH,
                                                 const float* __restrict__ b2,
                                                 float* __restrict__ out) {
    const int jt = blockIdx.x;
    const int it = blockIdx.y;
    const int b  = blockIdx.z;
    const int tid = threadIdx.x;
    const int wv = tid >> 6, l = tid & 63;
    const int lhi = l >> 4, dj = l & 15;
    const int i0 = it * 4, j0 = jt * 16;
    const int i = i0 + wv, j = j0 + dj;

    __shared__ char smem[SMEMB];

    const float S = 1.f / 384.f;
    const int r0 = corner_cell(-1.f + (2 * i0 + 1) / 384.f, -S);
    const int r1 = corner_cell(-1.f + (2 * (i0 + 3) + 1) / 384.f, +S);
    const int c0 = corner_cell(-1.f + (2 * j0 + 1) / 384.f, -S);
    const int c1 = corner_cell(-1.f + (2 * (j0 + 15) + 1) / 384.f, +S);
    const int nc = c1 - c0 + 1;
    const int ncell = (r1 - r0 + 1) * nc;

    // ---- stage: cells (f16), uv (f16 from UVH), W2F (32 KB)
    {
        int cell = tid >> 5, c16 = tid & 31;
        if (cell < ncell) {
            const float rcp_nc = 1.f / (float)nc;
            int cr = (int)((float)cell * rcp_nc);
            int cc2 = cell - cr * nc;
            const _Float16* src = G + (((size_t)((b << 12) + ((r0 + cr) << 6) + (c0 + cc2))) << 8) + (c16 << 3);
            *(f32x4*)(smem + cell * CELLB + (c16 << 4)) = *(const f32x4*)src;
        }
        if (tid < 64)
            *(f32x4*)(smem + UVB + (tid << 4)) = *(const f32x4*)(UVH + (tid << 3));
        const f32x4* w2g = (const f32x4*)W2F;
#pragma unroll
        for (int t = 0; t < 8; ++t)
            *(f32x4*)(smem + W2B + ((t * 256 + tid) << 4)) = w2g[t * 256 + tid];
    }
    __syncthreads();

    // ---- per-pixel corner setup
    const float cyq = -1.f + (2 * i + 1) / 384.f;
    const float cxq = -1.f + (2 * j + 1) / 384.f;
    const int iym = corner_cell(cyq, -S), iyp = corner_cell(cyq, +S);
    const int ixm = corner_cell(cxq, -S), ixp = corner_cell(cxq, +S);
    const float ry0 = (cyq - (-1.f + (2 * iym + 1) / 64.f)) * 64.f;
    const float ry1 = (cyq - (-1.f + (2 * iyp + 1) / 64.f)) * 64.f;
    const float rx0 = (cxq - (-1.f + (2 * ixm + 1) / 64.f)) * 64.f;
    const float rx1 = (cxq - (-1.f + (2 * ixp + 1) / 64.f)) * 64.f;
    const bool ys = (iyp != iym), xs = (ixp != ixm);
    const float a0 = fabsf(ry0 * rx0) + 1e-9f;
    const float a1 = fabsf(ry0 * (xs ? rx1 : rx0)) + 1e-9f;
    const float a2 = fabsf((ys ? ry1 : ry0) * rx0) + 1e-9f;
    const float a3 = fabsf((ys ? ry1 : ry0) * (xs ? rx1 : rx0)) + 1e-9f;
    const float inv = 1.f / (a0 + a1 + a2 + a3);
    const float g0w = a3 * inv, g1w = a2 * inv, g2w = a1 * inv, g3w = a0 * inv;
    float W00 = g0w, W01 = 0.f, W10 = 0.f, W11 = 0.f;
    if (xs) W01 += g1w; else W00 += g1w;
    if (ys) W10 += g2w; else W00 += g2w;
    if (ys && xs) W11 += g3w;
    else if (ys)  W10 += g3w;
    else if (xs)  W01 += g3w;
    else          W00 += g3w;

#define DUP2(x) (f16x2){(_Float16)(x), (_Float16)(x)}
    const f16x2 ry0h = DUP2(ry0), ry1h = DUP2(ry1);
    const f16x2 rx0h = DUP2(rx0), rx1h = DUP2(rx1);
    const f16x2 W00h = DUP2(W00), W01h = DUP2(W01);
    const f16x2 W10h = DUP2(W10), W11h = DUP2(W11);

    const int lo16 = lhi << 4;
    const char* cell00 = smem + ((iym - r0) * nc + (ixm - c0)) * CELLB + lo16;
    const char* cell01 = smem + ((iym - r0) * nc + (ixp - c0)) * CELLB + lo16;
    const char* cell10 = smem + ((iyp - r0) * nc + (ixm - c0)) * CELLB + lo16;
    const char* cell11 = smem + ((iyp - r0) * nc + (ixp - c0)) * CELLB + lo16;
    const char* uvp = smem + UVB + lo16;
    const f16x8* w2l = (const f16x8*)(smem + W2B) + l;

    f32x4 acc[4];
#pragma unroll
    for (int ng = 0; ng < 4; ++ng) acc[ng] = (f32x4){0.f, 0.f, 0.f, 0.f};

#define NODE(cp, ryh, rxh, Wh) {                                           \
        f16x8 gv = *(const f16x8*)((cp) + ko);                             \
        f16x2 g2;                                                          \
        _Pragma("unroll")                                                  \
        for (int e = 0; e < 4; ++e) {                                      \
            g2[0] = gv[2*e]; g2[1] = gv[2*e+1];                            \
            f16x2 t = g2 + (ryh) * uu[e] + (rxh) * vv[e];                  \
            t = __builtin_elementwise_max(t, (f16x2){(_Float16)0.f, (_Float16)0.f}); \
            h[e] += (Wh) * t;                                              \
        } }

#pragma unroll
    for (int ks = 0; ks < 8; ++ks) {
        const int ko = ks * 64;
        f16x8 uraw = *(const f16x8*)(uvp + ko);
        f16x8 vraw = *(const f16x8*)(uvp + 512 + ko);
        f16x2 uu[4], vv[4];
#pragma unroll
        for (int e = 0; e < 4; ++e) {
            uu[e][0] = uraw[2*e]; uu[e][1] = uraw[2*e+1];
            vv[e][0] = vraw[2*e]; vv[e][1] = vraw[2*e+1];
        }
        f16x2 h[4] = {};
        NODE(cell00, ry0h, rx0h, W00h);
        NODE(cell01, ry0h, rx1h, W01h);
        if (ys) {
            NODE(cell10, ry1h, rx0h, W10h);
            NODE(cell11, ry1h, rx1h, W11h);
        }
        f16x8 af;
#pragma unroll
        for (int e = 0; e < 4; ++e) { af[2*e] = h[e][0]; af[2*e+1] = h[e][1]; }
#pragma unroll
        for (int ng = 0; ng < 4; ++ng)
            acc[ng] = __builtin_amdgcn_mfma_f32_16x16x32_f16(af, w2l[(ks * 4 + ng) * 64], acc[ng], 0, 0, 0);
    }
#undef NODE

    // ---- epilogue: direct stores
#pragma unroll
    for (int ng = 0; ng < 4; ++ng) {
        const int o = (ng << 4) + dj;
        const float bb = b2[o];
        float* op = out + (((size_t)b * NOUT + o) * HOUT + i) * HOUT + j0 + (lhi << 2);
#pragma unroll
        for (int r = 0; r < 4; ++r)
            op[r] = acc[ng][r] + bb;
    }
}

extern "C" void kernel_launch(void* const* d_in, const int* in_sizes, int n_in,
                              void* d_out, int out_size, void* d_ws, size_t ws_size,
                              hipStream_t stream) {
    const float* res = (const float*)d_in[0];
    const float* w1  = (const float*)d_in[1];
    const float* b1  = (const float*)d_in[2];
    const float* w2  = (const float*)d_in[3];
    const float* b2  = (const float*)d_in[4];
    float* out = (float*)d_out;

    char* ws = (char*)d_ws;
    _Float16* G   = (_Float16*)ws;                              // 4 MB
    _Float16* W2F = (_Float16*)(ws + (size_t)(8u << 20));       // 32 KB
    _Float16* W1F = (_Float16*)(ws + (size_t)(8u << 20) + 65536);
    _Float16* UVH = (_Float16*)(ws + (size_t)(8u << 20) + 131072);

    k_prep<<<130, 256, 0, stream>>>(w1, w2, W2F, W1F, UVH);
    k_gfeat<<<256, 256, 0, stream>>>(res, W1F, b1, G);
    k_main<<<dim3(24, 96, 2), 256, 0, stream>>>(G, W2F, UVH, b2, out);
}